// Round 1
// baseline (657.207 us; speedup 1.0000x reference)
//
#include <hip/hip_runtime.h>
#include <math.h>

#define NN 512
#define DD 256
#define CC 128
#define LL 144

// swizzled LDS float-index for 64x128 tile; c4 must be a multiple of 4
__device__ __forceinline__ int swzv(int r, int c4) {
  return (r << 7) + (c4 ^ (((r >> 2) & 7) << 2));
}

__global__ __launch_bounds__(128) void preds1_kernel(
    const float* __restrict__ f_t, const float* __restrict__ W1,
    const float* __restrict__ b1, float* __restrict__ preds1) {
  __shared__ float frow[DD];
  int n = blockIdx.x;
  int c = threadIdx.x;
  for (int d = c; d < DD; d += 128) frow[d] = f_t[n * DD + d];
  __syncthreads();
  const float* w = W1 + c * DD;
  float acc = b1[c];
#pragma unroll 8
  for (int d = 0; d < DD; d += 4) {
    float4 wv = *(const float4*)(w + d);
    acc = fmaf(frow[d], wv.x, acc);
    acc = fmaf(frow[d + 1], wv.y, acc);
    acc = fmaf(frow[d + 2], wv.z, acc);
    acc = fmaf(frow[d + 3], wv.w, acc);
  }
  preds1[n * CC + c] = acc;
}

__global__ __launch_bounds__(256, 2) void main_kernel(
    const float* __restrict__ preds1,
    const float* __restrict__ fmap_t, const float* __restrict__ fmap_tp1,
    const float* __restrict__ W2, const float* __restrict__ b2,
    float* __restrict__ out) {
  __shared__ __align__(16) float A[64 * CC];  // preds rows (swizzled)
  __shared__ __align__(16) float B[64 * CC];  // pos / W2 tile (swizzled)

  const int bid = blockIdx.x;
  const int l = bid >> 4;
  const int sub = bid & 15;
  const int is2 = sub & 1;   // block-uniform
  const int rb = sub >> 1;   // row-block (64 rows)
  const int t = threadIdx.x;
  const int tx = t & 15;     // m-tile coord (4 m's)
  const int ty = t >> 4;     // row coord (4 rows)

  if (!is2) {
    // stage preds1 rows into A
    for (int idx = t * 4; idx < 64 * CC; idx += 1024) {
      int rr = idx >> 7, cc = idx & 127;
      float4 v = *(const float4*)(preds1 + (rb * 64 + rr) * CC + cc);
      *(float4*)(A + swzv(rr, cc)) = v;
    }
  } else {
    // compute preds2 rows = loc @ W2^T + b2 into A
    const int r = t >> 2, q = t & 3;
    const int row = rb * 64 + r;
    float loc[32];
    const float* lp = fmap_t + (size_t)row * (LL * CC) + l * CC + q * 32;
#pragma unroll
    for (int i = 0; i < 32; i += 4) {
      float4 v = *(const float4*)(lp + i);
      loc[i] = v.x; loc[i + 1] = v.y; loc[i + 2] = v.z; loc[i + 3] = v.w;
    }
    for (int dt = 0; dt < 2; ++dt) {
      __syncthreads();
      for (int idx = t * 4; idx < 64 * CC; idx += 1024) {
        int rr = idx >> 7, cc = idx & 127;
        float4 v = *(const float4*)(W2 + dt * 64 * CC + idx);
        *(float4*)(B + swzv(rr, cc)) = v;
      }
      __syncthreads();
#pragma unroll 4
      for (int dd = 0; dd < 64; ++dd) {
        float p = 0.f;
#pragma unroll
        for (int i = 0; i < 32; i += 4) {
          float4 wv = *(const float4*)(B + swzv(dd, q * 32 + i));
          p = fmaf(loc[i], wv.x, p);
          p = fmaf(loc[i + 1], wv.y, p);
          p = fmaf(loc[i + 2], wv.z, p);
          p = fmaf(loc[i + 3], wv.w, p);
        }
        p += __shfl_xor(p, 1);
        p += __shfl_xor(p, 2);
        int d = dt * 64 + dd;
        if (q == (dd & 3)) {
          int c4 = d & ~3;
          A[(r << 7) + (c4 ^ (((r >> 2) & 7) << 2)) + (d & 3)] = p + b2[d];
        }
      }
    }
  }
  __syncthreads();

  // online LSE over m for 4 rows per thread (rows row0..row0+3, m's from tx)
  float mx[4] = {-INFINITY, -INFINITY, -INFINITY, -INFINITY};
  float sm[4] = {0.f, 0.f, 0.f, 0.f};
  float dg[4] = {0.f, 0.f, 0.f, 0.f};
  const int row0 = rb * 64 + ty * 4;
  const int kA = (ty & 7) << 2;
  const int kB = (tx & 7) << 2;
  int baseA[4], baseB[4];
#pragma unroll
  for (int i = 0; i < 4; ++i) baseA[i] = (ty * 4 + i) << 7;
#pragma unroll
  for (int j = 0; j < 4; ++j) baseB[j] = (tx * 4 + j) << 7;

  for (int mt = 0; mt < NN / 64; ++mt) {
    for (int idx = t * 4; idx < 64 * CC; idx += 1024) {
      int mm = idx >> 7, cc = idx & 127;
      float4 v = *(const float4*)(fmap_tp1 +
          (size_t)(mt * 64 + mm) * (LL * CC) + l * CC + cc);
      *(float4*)(B + swzv(mm, cc)) = v;
    }
    __syncthreads();

    float acc[4][4];
#pragma unroll
    for (int i = 0; i < 4; ++i)
#pragma unroll
      for (int j = 0; j < 4; ++j) acc[i][j] = 0.f;

#pragma unroll 4
    for (int c = 0; c < CC; c += 4) {
      const int ofsA = c ^ kA;
      const int ofsB = c ^ kB;
      float4 av[4], bv[4];
#pragma unroll
      for (int i = 0; i < 4; ++i) av[i] = *(const float4*)(A + baseA[i] + ofsA);
#pragma unroll
      for (int j = 0; j < 4; ++j) bv[j] = *(const float4*)(B + baseB[j] + ofsB);
#pragma unroll
      for (int i = 0; i < 4; ++i)
#pragma unroll
        for (int j = 0; j < 4; ++j) {
          acc[i][j] = fmaf(av[i].x, bv[j].x, acc[i][j]);
          acc[i][j] = fmaf(av[i].y, bv[j].y, acc[i][j]);
          acc[i][j] = fmaf(av[i].z, bv[j].z, acc[i][j]);
          acc[i][j] = fmaf(av[i].w, bv[j].w, acc[i][j]);
        }
    }

    const int mbase = mt * 64 + tx * 4;
#pragma unroll
    for (int i = 0; i < 4; ++i) {
#pragma unroll
      for (int j = 0; j < 4; ++j)
        if (mbase + j == row0 + i) dg[i] += acc[i][j];
      float tmax = fmaxf(fmaxf(acc[i][0], acc[i][1]),
                         fmaxf(acc[i][2], acc[i][3]));
      float M = fmaxf(mx[i], tmax);
      float s = __expf(acc[i][0] - M) + __expf(acc[i][1] - M) +
                __expf(acc[i][2] - M) + __expf(acc[i][3] - M);
      sm[i] = sm[i] * __expf(mx[i] - M) + s;
      mx[i] = M;
    }
    __syncthreads();
  }

  // merge the 16 tx-lanes per row, then block-reduce
  float contrib = 0.f;
#pragma unroll
  for (int i = 0; i < 4; ++i) {
    float m_ = mx[i], s_ = sm[i], d_ = dg[i];
#pragma unroll
    for (int st = 1; st <= 8; st <<= 1) {
      float m2 = __shfl_xor(m_, st);
      float s2 = __shfl_xor(s_, st);
      float M = fmaxf(m_, m2);
      s_ = s_ * __expf(m_ - M) + s2 * __expf(m2 - M);
      m_ = M;
      d_ += __shfl_xor(d_, st);
    }
    if (tx == 0) contrib += m_ + __logf(s_) - d_;
  }
  // reuse A as reduction scratch (all A reads completed before last barrier)
  if (tx == 0) A[ty] = contrib;
  __syncthreads();
  if (t == 0) {
    float s = 0.f;
#pragma unroll
    for (int i = 0; i < 16; ++i) s += A[i];
    atomicAdd(out, s * (1.0f / (LL * NN)));
  }
}

extern "C" void kernel_launch(void* const* d_in, const int* in_sizes, int n_in,
                              void* d_out, int out_size, void* d_ws, size_t ws_size,
                              hipStream_t stream) {
  const float* f_t      = (const float*)d_in[0];
  const float* fmap_t   = (const float*)d_in[1];
  const float* fmap_tp1 = (const float*)d_in[2];
  const float* W1       = (const float*)d_in[3];
  const float* b1       = (const float*)d_in[4];
  const float* W2       = (const float*)d_in[5];
  const float* b2       = (const float*)d_in[6];
  float* out = (float*)d_out;
  float* preds1 = (float*)d_ws;  // 512*128 floats = 256 KB

  hipMemsetAsync(d_out, 0, out_size * sizeof(float), stream);
  preds1_kernel<<<NN, 128, 0, stream>>>(f_t, W1, b1, preds1);
  main_kernel<<<LL * 16, 256, 0, stream>>>(preds1, fmap_t, fmap_tp1, W2, b2, out);
}

// Round 2
// 213.704 us; speedup vs baseline: 3.0753x; 3.0753x over previous
//
#include <hip/hip_runtime.h>
#include <hip/hip_bf16.h>
#include <math.h>

#define NNq 512
#define CCq 128
#define LLq 144
#define LC (LLq * CCq)  // 18432
#define LOG2E 1.4426950408889634f

typedef short bf16x8 __attribute__((ext_vector_type(8)));
typedef float f32x4 __attribute__((ext_vector_type(4)));

__device__ __forceinline__ float fast_exp2(float x) {
#if __has_builtin(__builtin_amdgcn_exp2f)
  return __builtin_amdgcn_exp2f(x);
#else
  return exp2f(x);
#endif
}
__device__ __forceinline__ float fast_log2(float x) {
#if __has_builtin(__builtin_amdgcn_logf)
  return __builtin_amdgcn_logf(x);
#else
  return log2f(x);
#endif
}

__device__ __forceinline__ ushort f2bf(float x) {
  __hip_bfloat16 h = __float2bfloat16(x);
  return __builtin_bit_cast(ushort, h);
}

// byte offset into a 256-byte-row swizzled LDS tile
__device__ __forceinline__ int swb(int row, int x) {
  return (row << 8) + (x ^ ((row & 15) << 4));
}

// stage a 64x128 fp32 tile (row stride srow floats) -> swizzled bf16 LDS
__device__ __forceinline__ void stage64(ushort* dst, const float* __restrict__ src,
                                        int srow, int t) {
#pragma unroll
  for (int k = 0; k < 4; ++k) {
    int idx = t + k * 512;
    int row = idx >> 5, c4 = (idx & 31) << 2;
    float4 v = *(const float4*)(src + (size_t)row * srow + c4);
    ushort4 h = {f2bf(v.x), f2bf(v.y), f2bf(v.z), f2bf(v.w)};
    *(ushort4*)((char*)dst + swb(row, c4 << 1)) = h;
  }
}

// preds1 = (f_t @ W1^T + b1) * log2e, stored as swizzled bf16 image [8][64][128]
__global__ __launch_bounds__(512, 1) void preds1_mfma(
    const float* __restrict__ f_t, const float* __restrict__ W1,
    const float* __restrict__ b1, ushort* __restrict__ p1img) {
  __shared__ __align__(16) ushort sF[64 * 256];   // 32 KB
  __shared__ __align__(16) ushort sW[128 * 256];  // 64 KB
  const int t = threadIdx.x, rb = blockIdx.x;
#pragma unroll
  for (int k = 0; k < 8; ++k) {  // f_t rows: 64 x 64 float4-chunks
    int idx = t + k * 512;
    int row = idx >> 6, c4 = (idx & 63) << 2;
    float4 v = *(const float4*)(f_t + (size_t)(rb * 64 + row) * 256 + c4);
    ushort4 h = {f2bf(v.x), f2bf(v.y), f2bf(v.z), f2bf(v.w)};
    *(ushort4*)((char*)sF + (row << 9) + ((c4 << 1) ^ ((row & 15) << 4))) = h;
  }
#pragma unroll
  for (int k = 0; k < 16; ++k) {  // W1: 128 x 64 chunks
    int idx = t + k * 512;
    int row = idx >> 6, c4 = (idx & 63) << 2;
    float4 v = *(const float4*)(W1 + (size_t)row * 256 + c4);
    ushort4 h = {f2bf(v.x), f2bf(v.y), f2bf(v.z), f2bf(v.w)};
    *(ushort4*)((char*)sW + (row << 9) + ((c4 << 1) ^ ((row & 15) << 4))) = h;
  }
  __syncthreads();
  const int wave = t >> 6, lane = t & 63, lo = lane & 15, hi = lane >> 4;
  const int pr = (wave & 1) * 32, pd = (wave >> 1) * 32;
  f32x4 a00 = {}, a01 = {}, a10 = {}, a11 = {};
#pragma unroll
  for (int s = 0; s < 8; ++s) {
    int x = s * 64 + hi * 16;
    int r0 = pr + lo, r1 = pr + 16 + lo;
    int d0 = pd + lo, d1 = pd + 16 + lo;
    bf16x8 fa0 = *(const bf16x8*)((const char*)sF + (r0 << 9) + (x ^ ((r0 & 15) << 4)));
    bf16x8 fa1 = *(const bf16x8*)((const char*)sF + (r1 << 9) + (x ^ ((r1 & 15) << 4)));
    bf16x8 wb0 = *(const bf16x8*)((const char*)sW + (d0 << 9) + (x ^ ((d0 & 15) << 4)));
    bf16x8 wb1 = *(const bf16x8*)((const char*)sW + (d1 << 9) + (x ^ ((d1 & 15) << 4)));
    a00 = __builtin_amdgcn_mfma_f32_16x16x32_bf16(fa0, wb0, a00, 0, 0, 0);
    a01 = __builtin_amdgcn_mfma_f32_16x16x32_bf16(fa0, wb1, a01, 0, 0, 0);
    a10 = __builtin_amdgcn_mfma_f32_16x16x32_bf16(fa1, wb0, a10, 0, 0, 0);
    a11 = __builtin_amdgcn_mfma_f32_16x16x32_bf16(fa1, wb1, a11, 0, 0, 0);
  }
  const float b1a = b1[pd + lo], b1b = b1[pd + 16 + lo];
#pragma unroll
  for (int rt = 0; rt < 2; ++rt)
#pragma unroll
    for (int ct = 0; ct < 2; ++ct)
#pragma unroll
      for (int i = 0; i < 4; ++i) {
        float v = rt ? (ct ? a11[i] : a10[i]) : (ct ? a01[i] : a00[i]);
        int rr = pr + rt * 16 + hi * 4 + i;
        int d = pd + ct * 16 + lo;
        ushort hv = f2bf((v + (ct ? b1b : b1a)) * LOG2E);
        *(ushort*)((char*)p1img + ((size_t)rb << 14) + (rr << 8) +
                   ((2 * d) ^ ((rr & 15) << 4))) = hv;
      }
}

__global__ __launch_bounds__(512, 4) void stdim_main(
    const ushort* __restrict__ p1img, const float* __restrict__ fmap_t,
    const float* __restrict__ fmap_tp1, const float* __restrict__ W2,
    const float* __restrict__ b2, float* __restrict__ out) {
  __shared__ __align__(16) ushort sA1[64 * 128];   // preds1 tile
  __shared__ __align__(16) ushort sA2[64 * 128];   // loc -> preds2 tile
  __shared__ __align__(16) ushort sB[2][64 * 128]; // pos tiles (dbuf) / W2-low
  __shared__ float s_rows[2][64][2];
  __shared__ float s_diag[2][64];
  __shared__ float s_red[8];

  const int bid = blockIdx.x;
  const int l = bid >> 3, rb = bid & 7;
  const int t = threadIdx.x;
  const int wave = t >> 6, lane = t & 63, lo = lane & 15, hi = lane >> 4;

  // ---- phase 0: loc -> sA2 ; W2 -> sB[0](d<64) + sA1(d>=64) ----
  stage64(sA2, fmap_t + (size_t)(rb * 64) * LC + l * CCq, LC, t);
#pragma unroll
  for (int k = 0; k < 8; ++k) {
    int idx = t + k * 512;
    int row = idx >> 5, c4 = (idx & 31) << 2;
    float4 v = *(const float4*)(W2 + (size_t)row * CCq + c4);
    ushort4 h = {f2bf(v.x), f2bf(v.y), f2bf(v.z), f2bf(v.w)};
    ushort* dst = (row < 64) ? sB[0] : sA1;
    *(ushort4*)((char*)dst + swb(row & 63, c4 << 1)) = h;
  }
  const int pr = (wave & 1) * 32, pd = (wave >> 1) * 32;
  const float b2a = b2[pd + lo], b2b = b2[pd + 16 + lo];
  __syncthreads();

  // ---- preds2 = loc @ W2^T via MFMA ----
  f32x4 p00 = {}, p01 = {}, p10 = {}, p11 = {};
  const ushort* wsrc = (pd < 64) ? sB[0] : sA1;
  const int pdl = pd & 63;
#pragma unroll
  for (int s = 0; s < 4; ++s) {
    int x = s * 64 + hi * 16;
    bf16x8 la0 = *(const bf16x8*)((const char*)sA2 + swb(pr + lo, x));
    bf16x8 la1 = *(const bf16x8*)((const char*)sA2 + swb(pr + 16 + lo, x));
    bf16x8 wb0 = *(const bf16x8*)((const char*)wsrc + swb(pdl + lo, x));
    bf16x8 wb1 = *(const bf16x8*)((const char*)wsrc + swb(pdl + 16 + lo, x));
    p00 = __builtin_amdgcn_mfma_f32_16x16x32_bf16(la0, wb0, p00, 0, 0, 0);
    p01 = __builtin_amdgcn_mfma_f32_16x16x32_bf16(la0, wb1, p01, 0, 0, 0);
    p10 = __builtin_amdgcn_mfma_f32_16x16x32_bf16(la1, wb0, p10, 0, 0, 0);
    p11 = __builtin_amdgcn_mfma_f32_16x16x32_bf16(la1, wb1, p11, 0, 0, 0);
  }
  __syncthreads();

  // ---- write preds2*log2e -> sA2 ; copy preds1 image -> sA1 ; stage pos mt=0 ----
#pragma unroll
  for (int rt = 0; rt < 2; ++rt)
#pragma unroll
    for (int ct = 0; ct < 2; ++ct)
#pragma unroll
      for (int i = 0; i < 4; ++i) {
        float v = rt ? (ct ? p11[i] : p10[i]) : (ct ? p01[i] : p00[i]);
        int rr = pr + rt * 16 + hi * 4 + i;
        int d = pd + ct * 16 + lo;
        *(ushort*)((char*)sA2 + (rr << 8) + ((2 * d) ^ ((rr & 15) << 4))) =
            f2bf((v + (ct ? b2b : b2a)) * LOG2E);
      }
#pragma unroll
  for (int k = 0; k < 2; ++k) {
    int idx = t + k * 512;
    ((float4*)sA1)[idx] = ((const float4*)((const char*)p1img + ((size_t)rb << 14)))[idx];
  }
  stage64(sB[0], fmap_tp1 + l * CCq, LC, t);
  __syncthreads();

  // ---- big loop: logits = preds @ pos^T, online sum of 2^w ----
  const int ty_ = wave >> 2, wr = (wave >> 1) & 1, wc = wave & 1;
  const ushort* At = ty_ ? sA2 : sA1;
  bf16x8 af[2][4];
#pragma unroll
  for (int rt = 0; rt < 2; ++rt)
#pragma unroll
    for (int s = 0; s < 4; ++s)
      af[rt][s] = *(const bf16x8*)((const char*)At +
                                   swb(wr * 32 + rt * 16 + lo, s * 64 + hi * 16));

  float sm0[4] = {0.f, 0.f, 0.f, 0.f}, sm1[4] = {0.f, 0.f, 0.f, 0.f};

  for (int mt = 0; mt < 8; ++mt) {
    if (mt < 7)
      stage64(sB[(mt + 1) & 1],
              fmap_tp1 + (size_t)((mt + 1) * 64) * LC + l * CCq, LC, t);
    const ushort* cur = sB[mt & 1];
    f32x4 a00 = {}, a01 = {}, a10 = {}, a11 = {};
#pragma unroll
    for (int s = 0; s < 4; ++s) {
      int x = s * 64 + hi * 16;
      bf16x8 b0 = *(const bf16x8*)((const char*)cur + swb(wc * 32 + lo, x));
      bf16x8 b1 = *(const bf16x8*)((const char*)cur + swb(wc * 32 + 16 + lo, x));
      a00 = __builtin_amdgcn_mfma_f32_16x16x32_bf16(af[0][s], b0, a00, 0, 0, 0);
      a01 = __builtin_amdgcn_mfma_f32_16x16x32_bf16(af[0][s], b1, a01, 0, 0, 0);
      a10 = __builtin_amdgcn_mfma_f32_16x16x32_bf16(af[1][s], b0, a10, 0, 0, 0);
      a11 = __builtin_amdgcn_mfma_f32_16x16x32_bf16(af[1][s], b1, a11, 0, 0, 0);
    }
#pragma unroll
    for (int i = 0; i < 4; ++i) {
      sm0[i] += fast_exp2(a00[i]) + fast_exp2(a01[i]);
      sm1[i] += fast_exp2(a10[i]) + fast_exp2(a11[i]);
    }
    if (mt == rb && wc == wr) {
#pragma unroll
      for (int i = 0; i < 4; ++i) {
        if (lo == hi * 4 + i) {
          s_diag[ty_][wr * 32 + hi * 4 + i] = a00[i];
          s_diag[ty_][wr * 32 + 16 + hi * 4 + i] = a11[i];
        }
      }
    }
    __syncthreads();
  }

  // ---- reduce: sum over the 16 lanes of each row-group ----
#pragma unroll
  for (int i = 0; i < 4; ++i) {
    float v0 = sm0[i], v1 = sm1[i];
#pragma unroll
    for (int st = 1; st <= 8; st <<= 1) {
      v0 += __shfl_xor(v0, st);
      v1 += __shfl_xor(v1, st);
    }
    sm0[i] = v0;
    sm1[i] = v1;
  }
  if (lo == 0) {
#pragma unroll
    for (int i = 0; i < 4; ++i) {
      s_rows[ty_][wr * 32 + hi * 4 + i][wc] = sm0[i];
      s_rows[ty_][wr * 32 + 16 + hi * 4 + i][wc] = sm1[i];
    }
  }
  __syncthreads();

  float part = 0.f;
  if (t < 128) {
    int ty = t >> 6, r = t & 63;
    float tot = s_rows[ty][r][0] + s_rows[ty][r][1];
    part = fast_log2(tot) - s_diag[ty][r];
  }
#pragma unroll
  for (int st = 1; st <= 32; st <<= 1) part += __shfl_xor(part, st);
  if (lane == 0) s_red[wave] = part;
  __syncthreads();
  if (t == 0) {
    float s = 0.f;
#pragma unroll
    for (int w = 0; w < 8; ++w) s += s_red[w];
    atomicAdd(out, s * (0.6931471805599453f / 73728.0f));
  }
}

extern "C" void kernel_launch(void* const* d_in, const int* in_sizes, int n_in,
                              void* d_out, int out_size, void* d_ws, size_t ws_size,
                              hipStream_t stream) {
  const float* f_t      = (const float*)d_in[0];
  const float* fmap_t   = (const float*)d_in[1];
  const float* fmap_tp1 = (const float*)d_in[2];
  const float* W1       = (const float*)d_in[3];
  const float* b1       = (const float*)d_in[4];
  const float* W2       = (const float*)d_in[5];
  const float* b2       = (const float*)d_in[6];
  float* out = (float*)d_out;
  ushort* p1img = (ushort*)d_ws;  // 8 * 64 * 128 bf16 = 128 KB (swizzled)

  hipMemsetAsync(d_out, 0, out_size * sizeof(float), stream);
  preds1_mfma<<<8, 512, 0, stream>>>(f_t, W1, b1, p1img);
  stdim_main<<<LLq * 8, 512, 0, stream>>>(p1img, fmap_t, fmap_tp1, W2, b2, out);
}

// Round 4
// 166.810 us; speedup vs baseline: 3.9399x; 1.2811x over previous
//
#include <hip/hip_runtime.h>
#include <hip/hip_bf16.h>
#include <math.h>

#define LC 18432              // 144*128
#define LOG2E 1.4426950408889634f

typedef short bf16x8 __attribute__((ext_vector_type(8)));
typedef float f32x4 __attribute__((ext_vector_type(4)));

#define MFMA16 __builtin_amdgcn_mfma_f32_16x16x32_bf16

__device__ __forceinline__ float fast_exp2(float x) {
#if __has_builtin(__builtin_amdgcn_exp2f)
  return __builtin_amdgcn_exp2f(x);
#else
  return exp2f(x);
#endif
}
__device__ __forceinline__ float fast_log2(float x) {
#if __has_builtin(__builtin_amdgcn_logf)
  return __builtin_amdgcn_logf(x);
#else
  return log2f(x);
#endif
}

__device__ __forceinline__ ushort f2bf(float x) {
  __hip_bfloat16 h = __float2bfloat16(x);
  return __builtin_bit_cast(ushort, h);
}

// byte offset in a 256-byte-row swizzled tile (128 bf16 cols)
__device__ __forceinline__ int swb(int row, int x) {
  return (row << 8) + (x ^ ((row & 15) << 4));
}
// byte offset in a 512-byte-row swizzled tile (256 bf16 cols)
__device__ __forceinline__ int swb9(int row, int x) {
  return (row << 9) + (x ^ ((row & 15) << 4));
}

typedef const __attribute__((address_space(1))) unsigned int g_u32;
typedef __attribute__((address_space(3))) unsigned int l_u32;
__device__ __forceinline__ void gl_lds16(const ushort* g, ushort* l) {
  __builtin_amdgcn_global_load_lds((g_u32*)g, (l_u32*)l, 16, 0, 0);
}

// ---------------- prep: p1img / p2img / posimg ----------------
// grid: [0,16) preds1 | [16,1168) preds2 | [1168,2320) pos convert
__global__ __launch_bounds__(256) void prep_kernel(
    const float* __restrict__ f_t, const float* __restrict__ fmap_t,
    const float* __restrict__ fmap_tp1, const float* __restrict__ W1,
    const float* __restrict__ b1, const float* __restrict__ W2,
    const float* __restrict__ b2, ushort* __restrict__ p1img,
    ushort* __restrict__ p2img, ushort* __restrict__ posimg) {
  __shared__ __align__(16) ushort s_lds[32768];  // 64 KB
  const int bid = blockIdx.x, t = threadIdx.x;
  const int wave = t >> 6, lane = t & 63, lo = lane & 15, hi = lane >> 4;

  if (bid < 16) {
    // ---- preds1: rows rb*64..+63, d-cols dh*64..+63, K=256 ----
    const int rb = bid >> 1, dh = bid & 1;
    ushort* sF = s_lds;           // 64 x 256 bf16
    ushort* sW = s_lds + 16384;   // 64 x 256 bf16
#pragma unroll
    for (int k = 0; k < 16; ++k) {
      int idx = t + k * 256;
      int row = idx >> 6, c4 = (idx & 63) << 2;
      float4 v = *(const float4*)(f_t + (size_t)(rb * 64 + row) * 256 + c4);
      ushort4 h = {f2bf(v.x), f2bf(v.y), f2bf(v.z), f2bf(v.w)};
      *(ushort4*)((char*)sF + swb9(row, c4 << 1)) = h;
    }
#pragma unroll
    for (int k = 0; k < 16; ++k) {
      int idx = t + k * 256;
      int row = idx >> 6, c4 = (idx & 63) << 2;
      float4 v = *(const float4*)(W1 + (size_t)(dh * 64 + row) * 256 + c4);
      ushort4 h = {f2bf(v.x), f2bf(v.y), f2bf(v.z), f2bf(v.w)};
      *(ushort4*)((char*)sW + swb9(row, c4 << 1)) = h;
    }
    __syncthreads();
    const int wn = (wave & 1) * 32, wd = (wave >> 1) * 32;
    f32x4 acc[2][2] = {};
#pragma unroll
    for (int s = 0; s < 8; ++s) {
      int x = s * 64 + hi * 16;
      bf16x8 a0 = *(const bf16x8*)((const char*)sF + swb9(wn + lo, x));
      bf16x8 a1 = *(const bf16x8*)((const char*)sF + swb9(wn + 16 + lo, x));
#pragma unroll
      for (int j = 0; j < 2; ++j) {
        bf16x8 b = *(const bf16x8*)((const char*)sW + swb9(wd + j * 16 + lo, x));
        acc[0][j] = MFMA16(a0, b, acc[0][j], 0, 0, 0);
        acc[1][j] = MFMA16(a1, b, acc[1][j], 0, 0, 0);
      }
    }
    ushort* tile = p1img + (size_t)rb * 8192;
#pragma unroll
    for (int j = 0; j < 2; ++j) {
      int d = dh * 64 + wd + j * 16 + lo;
      float bb = b1[d];
#pragma unroll
      for (int i2 = 0; i2 < 2; ++i2)
#pragma unroll
        for (int e = 0; e < 4; ++e) {
          int r = wn + i2 * 16 + hi * 4 + e;
          *(ushort*)((char*)tile + (r << 8) + ((2 * d) ^ ((r & 15) << 4))) =
              f2bf((acc[i2][j][e] + bb) * LOG2E);
        }
    }
  } else if (bid < 1168) {
    // ---- preds2 tile (l, rb): 64 x 128, K=128 ----
    const int ba = bid - 16;
    const int l = ba >> 3, rb = ba & 7;
    ushort* sL = s_lds;          // 64 x 128
    ushort* sW = s_lds + 8192;   // 128 x 128
#pragma unroll
    for (int k = 0; k < 8; ++k) {
      int idx = t + k * 256;
      int row = idx >> 5, c4 = (idx & 31) << 2;
      float4 v = *(const float4*)(fmap_t + (size_t)(rb * 64 + row) * LC + l * 128 + c4);
      ushort4 h = {f2bf(v.x), f2bf(v.y), f2bf(v.z), f2bf(v.w)};
      *(ushort4*)((char*)sL + swb(row, c4 << 1)) = h;
    }
#pragma unroll
    for (int k = 0; k < 16; ++k) {
      int idx = t + k * 256;
      int row = idx >> 5, c4 = (idx & 31) << 2;
      float4 v = *(const float4*)(W2 + (size_t)row * 128 + c4);
      ushort4 h = {f2bf(v.x), f2bf(v.y), f2bf(v.z), f2bf(v.w)};
      *(ushort4*)((char*)sW + swb(row, c4 << 1)) = h;
    }
    __syncthreads();
    const int wn = (wave & 1) * 32, wd = (wave >> 1) * 64;
    f32x4 acc[2][4] = {};
#pragma unroll
    for (int s = 0; s < 4; ++s) {
      int x = s * 64 + hi * 16;
      bf16x8 a0 = *(const bf16x8*)((const char*)sL + swb(wn + lo, x));
      bf16x8 a1 = *(const bf16x8*)((const char*)sL + swb(wn + 16 + lo, x));
#pragma unroll
      for (int j = 0; j < 4; ++j) {
        bf16x8 b = *(const bf16x8*)((const char*)sW + swb(wd + j * 16 + lo, x));
        acc[0][j] = MFMA16(a0, b, acc[0][j], 0, 0, 0);
        acc[1][j] = MFMA16(a1, b, acc[1][j], 0, 0, 0);
      }
    }
    ushort* tile = p2img + (size_t)ba * 8192;
#pragma unroll
    for (int j = 0; j < 4; ++j) {
      int d = wd + j * 16 + lo;
      float bb = b2[d];
#pragma unroll
      for (int i2 = 0; i2 < 2; ++i2)
#pragma unroll
        for (int e = 0; e < 4; ++e) {
          int r = wn + i2 * 16 + hi * 4 + e;
          *(ushort*)((char*)tile + (r << 8) + ((2 * d) ^ ((r & 15) << 4))) =
              f2bf((acc[i2][j][e] + bb) * LOG2E);
        }
    }
  } else {
    // ---- posimg tile (l, mt): convert only ----
    const int bb = bid - 1168;
    const int l = bb >> 3, mt = bb & 7;
    ushort* tile = posimg + (size_t)bb * 8192;
#pragma unroll
    for (int k = 0; k < 8; ++k) {
      int idx = t + k * 256;
      int row = idx >> 5, c4 = (idx & 31) << 2;
      float4 v = *(const float4*)(fmap_tp1 + (size_t)(mt * 64 + row) * LC + l * 128 + c4);
      ushort4 h = {f2bf(v.x), f2bf(v.y), f2bf(v.z), f2bf(v.w)};
      *(ushort4*)((char*)tile + swb(row, c4 << 1)) = h;
    }
  }
}

// ---------------- main: logits + online sum of 2^w ----------------
__global__ __launch_bounds__(512) void stdim_main(
    const ushort* __restrict__ p1img, const ushort* __restrict__ p2img,
    const ushort* __restrict__ posimg, float* __restrict__ out) {
  __shared__ __align__(16) ushort sB[2][8192];  // pos tiles dbuf (swizzled)
  __shared__ float s_rows[2][64][2];
  __shared__ float s_diag[2][64];
  __shared__ float s_red[8];

  const int bid = blockIdx.x;
  const int work = (bid & 7) * 144 + (bid >> 3);  // XCD-chunked (1152 % 8 == 0)
  const int l = work >> 3, rb = work & 7;
  const int t = threadIdx.x;
  const int wave = t >> 6, lane = t & 63, lo = lane & 15, hi = lane >> 4;
  const int ty_ = wave >> 2, wr = (wave >> 1) & 1, wc = wave & 1;

  const ushort* ptile = posimg + (size_t)(l * 8) * 8192;

  // stage tile 0 (direct to LDS; dest linear == pre-swizzled image)
  {
    const ushort* src = ptile + wave * 1024 + lane * 8;
    ushort* dst = (ushort*)sB[0] + wave * 1024;
    gl_lds16(src, dst);
    gl_lds16(src + 512, dst + 512);
  }

  // A fragments for this wave (rows rb*64 + wr*32 + [0,32))
  const ushort* aimg = ty_ ? (p2img + (size_t)(l * 8 + rb) * 8192)
                           : (p1img + (size_t)rb * 8192);
  bf16x8 af[2][4];
#pragma unroll
  for (int rt = 0; rt < 2; ++rt)
#pragma unroll
    for (int s = 0; s < 4; ++s)
      af[rt][s] = *(const bf16x8*)((const char*)aimg +
                                   swb(wr * 32 + rt * 16 + lo, s * 64 + hi * 16));

  float sm0[4] = {0.f, 0.f, 0.f, 0.f}, sm1[4] = {0.f, 0.f, 0.f, 0.f};
  __syncthreads();  // tile 0 staged (barrier drains vmcnt)

  for (int mt = 0; mt < 8; ++mt) {
    const int cur = mt & 1;
    if (mt < 7) {  // prefetch next tile into the other buffer
      const ushort* src = ptile + (size_t)(mt + 1) * 8192 + wave * 1024 + lane * 8;
      ushort* dst = (ushort*)sB[cur ^ 1] + wave * 1024;
      gl_lds16(src, dst);
      gl_lds16(src + 512, dst + 512);
    }
    f32x4 a00 = {}, a01 = {}, a10 = {}, a11 = {};
#pragma unroll
    for (int s = 0; s < 4; ++s) {
      int x = s * 64 + hi * 16;
      bf16x8 b0 = *(const bf16x8*)((const char*)sB[cur] + swb(wc * 32 + lo, x));
      bf16x8 b1 = *(const bf16x8*)((const char*)sB[cur] + swb(wc * 32 + 16 + lo, x));
      a00 = MFMA16(af[0][s], b0, a00, 0, 0, 0);
      a01 = MFMA16(af[0][s], b1, a01, 0, 0, 0);
      a10 = MFMA16(af[1][s], b0, a10, 0, 0, 0);
      a11 = MFMA16(af[1][s], b1, a11, 0, 0, 0);
    }
#pragma unroll
    for (int i = 0; i < 4; ++i) {
      sm0[i] += fast_exp2(a00[i]) + fast_exp2(a01[i]);
      sm1[i] += fast_exp2(a10[i]) + fast_exp2(a11[i]);
    }
    if (mt == rb && wc == wr) {
#pragma unroll
      for (int i = 0; i < 4; ++i) {
        if (lo == hi * 4 + i) {
          s_diag[ty_][wr * 32 + hi * 4 + i] = a00[i];
          s_diag[ty_][wr * 32 + 16 + hi * 4 + i] = a11[i];
        }
      }
    }
    __syncthreads();
  }

  // reduce the 16 lo-lanes of each row-group
#pragma unroll
  for (int i = 0; i < 4; ++i) {
    float v0 = sm0[i], v1 = sm1[i];
#pragma unroll
    for (int st = 1; st <= 8; st <<= 1) {
      v0 += __shfl_xor(v0, st);
      v1 += __shfl_xor(v1, st);
    }
    sm0[i] = v0;
    sm1[i] = v1;
  }
  if (lo == 0) {
#pragma unroll
    for (int i = 0; i < 4; ++i) {
      s_rows[ty_][wr * 32 + hi * 4 + i][wc] = sm0[i];
      s_rows[ty_][wr * 32 + 16 + hi * 4 + i][wc] = sm1[i];
    }
  }
  __syncthreads();

  float part = 0.f;
  if (t < 128) {
    int ty = t >> 6, r = t & 63;
    float tot = s_rows[ty][r][0] + s_rows[ty][r][1];
    part = fast_log2(tot) - s_diag[ty][r];
  }
#pragma unroll
  for (int st = 1; st <= 32; st <<= 1) part += __shfl_xor(part, st);
  if (lane == 0) s_red[wave] = part;
  __syncthreads();
  if (t == 0) {
    float s = 0.f;
#pragma unroll
    for (int w = 0; w < 8; ++w) s += s_red[w];
    atomicAdd(out, s * (0.6931471805599453f / 73728.0f));
  }
}

extern "C" void kernel_launch(void* const* d_in, const int* in_sizes, int n_in,
                              void* d_out, int out_size, void* d_ws, size_t ws_size,
                              hipStream_t stream) {
  const float* f_t      = (const float*)d_in[0];
  const float* fmap_t   = (const float*)d_in[1];
  const float* fmap_tp1 = (const float*)d_in[2];
  const float* W1       = (const float*)d_in[3];
  const float* b1       = (const float*)d_in[4];
  const float* W2       = (const float*)d_in[5];
  const float* b2       = (const float*)d_in[6];
  float* out = (float*)d_out;

  // ws layout (bf16 images, all tiles pre-swizzled):
  //   p1img:  8   x 8192 ushorts (128 KB)   preds1 * log2e
  //   p2img:  1152x 8192 ushorts (18.9 MB)  preds2 * log2e
  //   posimg: 1152x 8192 ushorts (18.9 MB)  fmap_tp1 bf16
  ushort* p1img  = (ushort*)d_ws;
  ushort* p2img  = p1img + 8 * 8192;
  ushort* posimg = p2img + 1152 * 8192;

  hipMemsetAsync(d_out, 0, out_size * sizeof(float), stream);
  prep_kernel<<<2320, 256, 0, stream>>>(f_t, fmap_t, fmap_tp1, W1, b1, W2, b2,
                                        p1img, p2img, posimg);
  stdim_main<<<1152, 512, 0, stream>>>(p1img, p2img, posimg, out);
}

// Round 5
// 163.819 us; speedup vs baseline: 4.0118x; 1.0183x over previous
//
#include <hip/hip_runtime.h>
#include <hip/hip_bf16.h>
#include <math.h>

#define LC 18432              // 144*128
#define LOG2E 1.4426950408889634f

typedef short bf16x8 __attribute__((ext_vector_type(8)));
typedef float f32x4 __attribute__((ext_vector_type(4)));

#define MFMA16 __builtin_amdgcn_mfma_f32_16x16x32_bf16
#define WAITVM(N) asm volatile("s_waitcnt vmcnt(" #N ")" ::: "memory")

__device__ __forceinline__ float fast_exp2(float x) {
#if __has_builtin(__builtin_amdgcn_exp2f)
  return __builtin_amdgcn_exp2f(x);
#else
  return exp2f(x);
#endif
}
__device__ __forceinline__ float fast_log2(float x) {
#if __has_builtin(__builtin_amdgcn_logf)
  return __builtin_amdgcn_logf(x);
#else
  return log2f(x);
#endif
}

__device__ __forceinline__ ushort f2bf(float x) {
  __hip_bfloat16 h = __float2bfloat16(x);
  return __builtin_bit_cast(ushort, h);
}

// byte offset in a 256-byte-row swizzled tile (128 bf16 cols)
__device__ __forceinline__ int swb(int row, int x) {
  return (row << 8) + (x ^ ((row & 15) << 4));
}
// byte offset in a 512-byte-row swizzled tile (256 bf16 cols)
__device__ __forceinline__ int swb9(int row, int x) {
  return (row << 9) + (x ^ ((row & 15) << 4));
}

typedef const __attribute__((address_space(1))) unsigned int g_u32;
typedef __attribute__((address_space(3))) unsigned int l_u32;
__device__ __forceinline__ void gl_lds16(const ushort* g, ushort* l) {
  __builtin_amdgcn_global_load_lds((g_u32*)g, (l_u32*)l, 16, 0, 0);
}

// ---------------- prep: p1img / p2img / posimg ----------------
// grid: [0,16) preds1 | [16,1168) preds2 | [1168,2320) pos convert
__global__ __launch_bounds__(256) void prep_kernel(
    const float* __restrict__ f_t, const float* __restrict__ fmap_t,
    const float* __restrict__ fmap_tp1, const float* __restrict__ W1,
    const float* __restrict__ b1, const float* __restrict__ W2,
    const float* __restrict__ b2, ushort* __restrict__ p1img,
    ushort* __restrict__ p2img, ushort* __restrict__ posimg) {
  __shared__ __align__(16) ushort s_lds[32768];  // 64 KB
  const int bid = blockIdx.x, t = threadIdx.x;
  const int wave = t >> 6, lane = t & 63, lo = lane & 15, hi = lane >> 4;

  if (bid < 16) {
    // ---- preds1: rows rb*64..+63, d-cols dh*64..+63, K=256 ----
    const int rb = bid >> 1, dh = bid & 1;
    ushort* sF = s_lds;           // 64 x 256 bf16
    ushort* sW = s_lds + 16384;   // 64 x 256 bf16
#pragma unroll
    for (int k = 0; k < 16; ++k) {
      int idx = t + k * 256;
      int row = idx >> 6, c4 = (idx & 63) << 2;
      float4 v = *(const float4*)(f_t + (size_t)(rb * 64 + row) * 256 + c4);
      ushort4 h = {f2bf(v.x), f2bf(v.y), f2bf(v.z), f2bf(v.w)};
      *(ushort4*)((char*)sF + swb9(row, c4 << 1)) = h;
    }
#pragma unroll
    for (int k = 0; k < 16; ++k) {
      int idx = t + k * 256;
      int row = idx >> 6, c4 = (idx & 63) << 2;
      float4 v = *(const float4*)(W1 + (size_t)(dh * 64 + row) * 256 + c4);
      ushort4 h = {f2bf(v.x), f2bf(v.y), f2bf(v.z), f2bf(v.w)};
      *(ushort4*)((char*)sW + swb9(row, c4 << 1)) = h;
    }
    __syncthreads();
    const int wn = (wave & 1) * 32, wd = (wave >> 1) * 32;
    f32x4 acc[2][2] = {};
#pragma unroll
    for (int s = 0; s < 8; ++s) {
      int x = s * 64 + hi * 16;
      bf16x8 a0 = *(const bf16x8*)((const char*)sF + swb9(wn + lo, x));
      bf16x8 a1 = *(const bf16x8*)((const char*)sF + swb9(wn + 16 + lo, x));
#pragma unroll
      for (int j = 0; j < 2; ++j) {
        bf16x8 b = *(const bf16x8*)((const char*)sW + swb9(wd + j * 16 + lo, x));
        acc[0][j] = MFMA16(a0, b, acc[0][j], 0, 0, 0);
        acc[1][j] = MFMA16(a1, b, acc[1][j], 0, 0, 0);
      }
    }
    ushort* tile = p1img + (size_t)rb * 8192;
#pragma unroll
    for (int j = 0; j < 2; ++j) {
      int d = dh * 64 + wd + j * 16 + lo;
      float bb = b1[d];
#pragma unroll
      for (int i2 = 0; i2 < 2; ++i2)
#pragma unroll
        for (int e = 0; e < 4; ++e) {
          int r = wn + i2 * 16 + hi * 4 + e;
          *(ushort*)((char*)tile + (r << 8) + ((2 * d) ^ ((r & 15) << 4))) =
              f2bf((acc[i2][j][e] + bb) * LOG2E);
        }
    }
  } else if (bid < 1168) {
    // ---- preds2 tile (l, rb): 64 x 128, K=128 ----
    const int ba = bid - 16;
    const int l = ba >> 3, rb = ba & 7;
    ushort* sL = s_lds;          // 64 x 128
    ushort* sW = s_lds + 8192;   // 128 x 128
#pragma unroll
    for (int k = 0; k < 8; ++k) {
      int idx = t + k * 256;
      int row = idx >> 5, c4 = (idx & 31) << 2;
      float4 v = *(const float4*)(fmap_t + (size_t)(rb * 64 + row) * LC + l * 128 + c4);
      ushort4 h = {f2bf(v.x), f2bf(v.y), f2bf(v.z), f2bf(v.w)};
      *(ushort4*)((char*)sL + swb(row, c4 << 1)) = h;
    }
#pragma unroll
    for (int k = 0; k < 16; ++k) {
      int idx = t + k * 256;
      int row = idx >> 5, c4 = (idx & 31) << 2;
      float4 v = *(const float4*)(W2 + (size_t)row * 128 + c4);
      ushort4 h = {f2bf(v.x), f2bf(v.y), f2bf(v.z), f2bf(v.w)};
      *(ushort4*)((char*)sW + swb(row, c4 << 1)) = h;
    }
    __syncthreads();
    const int wn = (wave & 1) * 32, wd = (wave >> 1) * 64;
    f32x4 acc[2][4] = {};
#pragma unroll
    for (int s = 0; s < 4; ++s) {
      int x = s * 64 + hi * 16;
      bf16x8 a0 = *(const bf16x8*)((const char*)sL + swb(wn + lo, x));
      bf16x8 a1 = *(const bf16x8*)((const char*)sL + swb(wn + 16 + lo, x));
#pragma unroll
      for (int j = 0; j < 4; ++j) {
        bf16x8 b = *(const bf16x8*)((const char*)sW + swb(wd + j * 16 + lo, x));
        acc[0][j] = MFMA16(a0, b, acc[0][j], 0, 0, 0);
        acc[1][j] = MFMA16(a1, b, acc[1][j], 0, 0, 0);
      }
    }
    ushort* tile = p2img + (size_t)ba * 8192;
#pragma unroll
    for (int j = 0; j < 4; ++j) {
      int d = wd + j * 16 + lo;
      float bb = b2[d];
#pragma unroll
      for (int i2 = 0; i2 < 2; ++i2)
#pragma unroll
        for (int e = 0; e < 4; ++e) {
          int r = wn + i2 * 16 + hi * 4 + e;
          *(ushort*)((char*)tile + (r << 8) + ((2 * d) ^ ((r & 15) << 4))) =
              f2bf((acc[i2][j][e] + bb) * LOG2E);
        }
    }
  } else {
    // ---- posimg tile (l, mt): convert only ----
    const int bb = bid - 1168;
    const int l = bb >> 3, mt = bb & 7;
    ushort* tile = posimg + (size_t)bb * 8192;
#pragma unroll
    for (int k = 0; k < 8; ++k) {
      int idx = t + k * 256;
      int row = idx >> 5, c4 = (idx & 31) << 2;
      float4 v = *(const float4*)(fmap_tp1 + (size_t)(mt * 64 + row) * LC + l * 128 + c4);
      ushort4 h = {f2bf(v.x), f2bf(v.y), f2bf(v.z), f2bf(v.w)};
      *(ushort4*)((char*)tile + swb(row, c4 << 1)) = h;
    }
  }
}

// ---------------- main: logits + online sum of 2^w ----------------
// 4-buffer pipeline, prefetch depth 3, counted vmcnt, raw barriers.
__global__ __launch_bounds__(512) void stdim_main(
    const ushort* __restrict__ p1img, const ushort* __restrict__ p2img,
    const ushort* __restrict__ posimg, float* __restrict__ out) {
  __shared__ __align__(16) ushort sB[4][8192];  // 4 pos tile buffers (64 KB)
  __shared__ float s_rows[2][64][2];
  __shared__ float s_diag[2][64];
  __shared__ float s_red[8];

  const int bid = blockIdx.x;
  const int work = (bid & 7) * 144 + (bid >> 3);  // XCD-chunked (1152 % 8 == 0)
  const int l = work >> 3, rb = work & 7;
  const int t = threadIdx.x;
  const int wave = t >> 6, lane = t & 63, lo = lane & 15, hi = lane >> 4;
  const int ty_ = wave >> 2, wr = (wave >> 1) & 1, wc = wave & 1;

  const ushort* ptile = posimg + (size_t)(l * 8) * 8192;
  const ushort* gsrc = ptile + wave * 1024 + lane * 8;  // per-wave slice
  ushort* const ldst0 = (ushort*)sB[0] + wave * 1024;

  // ---- prologue: A-fragment loads + stage tiles 0,1,2; drain once ----
  const ushort* aimg = ty_ ? (p2img + (size_t)(l * 8 + rb) * 8192)
                           : (p1img + (size_t)rb * 8192);
  bf16x8 af[2][4];
#pragma unroll
  for (int rt = 0; rt < 2; ++rt)
#pragma unroll
    for (int s = 0; s < 4; ++s)
      af[rt][s] = *(const bf16x8*)((const char*)aimg +
                                   swb(wr * 32 + rt * 16 + lo, s * 64 + hi * 16));
#pragma unroll
  for (int pt = 0; pt < 3; ++pt) {
    gl_lds16(gsrc + (size_t)pt * 8192, ldst0 + pt * 8192);
    gl_lds16(gsrc + (size_t)pt * 8192 + 512, ldst0 + pt * 8192 + 512);
  }
  WAITVM(0);  // af + tiles 0-2 all landed (once per block)

  float sm0[4] = {0.f, 0.f, 0.f, 0.f}, sm1[4] = {0.f, 0.f, 0.f, 0.f};

#pragma unroll
  for (int mt = 0; mt < 8; ++mt) {
    // wait: oldest outstanding tile (= tile mt) complete; keep newer in flight
    if (mt < 6) WAITVM(4);
    else if (mt == 6) WAITVM(2);
    else WAITVM(0);
    __builtin_amdgcn_s_barrier();       // publish tile mt; WAR fence for issue below
    __builtin_amdgcn_sched_barrier(0);  // rule #18: pin reads after the wait

    if (mt <= 4) {  // issue tile mt+3 into buffer holding tile mt-1 (safe post-barrier)
      const ushort* src = gsrc + (size_t)(mt + 3) * 8192;
      ushort* dst = ldst0 + ((mt + 3) & 3) * 8192;
      gl_lds16(src, dst);
      gl_lds16(src + 512, dst + 512);
    }

    const ushort* cur = sB[mt & 3];
    f32x4 a00 = {}, a01 = {}, a10 = {}, a11 = {};
#pragma unroll
    for (int s = 0; s < 4; ++s) {
      int x = s * 64 + hi * 16;
      bf16x8 b0 = *(const bf16x8*)((const char*)cur + swb(wc * 32 + lo, x));
      bf16x8 b1 = *(const bf16x8*)((const char*)cur + swb(wc * 32 + 16 + lo, x));
      a00 = MFMA16(af[0][s], b0, a00, 0, 0, 0);
      a01 = MFMA16(af[0][s], b1, a01, 0, 0, 0);
      a10 = MFMA16(af[1][s], b0, a10, 0, 0, 0);
      a11 = MFMA16(af[1][s], b1, a11, 0, 0, 0);
    }
#pragma unroll
    for (int i = 0; i < 4; ++i) {
      sm0[i] += fast_exp2(a00[i]) + fast_exp2(a01[i]);
      sm1[i] += fast_exp2(a10[i]) + fast_exp2(a11[i]);
    }
    if (mt == rb && wc == wr) {
#pragma unroll
      for (int i = 0; i < 4; ++i) {
        if (lo == hi * 4 + i) {
          s_diag[ty_][wr * 32 + hi * 4 + i] = a00[i];
          s_diag[ty_][wr * 32 + 16 + hi * 4 + i] = a11[i];
        }
      }
    }
    // no end-of-iteration barrier: next iteration's top barrier is the fence
  }

  // reduce the 16 lo-lanes of each row-group
#pragma unroll
  for (int i = 0; i < 4; ++i) {
    float v0 = sm0[i], v1 = sm1[i];
#pragma unroll
    for (int st = 1; st <= 8; st <<= 1) {
      v0 += __shfl_xor(v0, st);
      v1 += __shfl_xor(v1, st);
    }
    sm0[i] = v0;
    sm1[i] = v1;
  }
  if (lo == 0) {
#pragma unroll
    for (int i = 0; i < 4; ++i) {
      s_rows[ty_][wr * 32 + hi * 4 + i][wc] = sm0[i];
      s_rows[ty_][wr * 32 + 16 + hi * 4 + i][wc] = sm1[i];
    }
  }
  __syncthreads();

  float part = 0.f;
  if (t < 128) {
    int ty = t >> 6, r = t & 63;
    float tot = s_rows[ty][r][0] + s_rows[ty][r][1];
    part = fast_log2(tot) - s_diag[ty][r];
  }
#pragma unroll
  for (int st = 1; st <= 32; st <<= 1) part += __shfl_xor(part, st);
  if (lane == 0) s_red[wave] = part;
  __syncthreads();
  if (t == 0) {
    float s = 0.f;
#pragma unroll
    for (int w = 0; w < 8; ++w) s += s_red[w];
    atomicAdd(out, s * (0.6931471805599453f / 73728.0f));
  }
}

extern "C" void kernel_launch(void* const* d_in, const int* in_sizes, int n_in,
                              void* d_out, int out_size, void* d_ws, size_t ws_size,
                              hipStream_t stream) {
  const float* f_t      = (const float*)d_in[0];
  const float* fmap_t   = (const float*)d_in[1];
  const float* fmap_tp1 = (const float*)d_in[2];
  const float* W1       = (const float*)d_in[3];
  const float* b1       = (const float*)d_in[4];
  const float* W2       = (const float*)d_in[5];
  const float* b2       = (const float*)d_in[6];
  float* out = (float*)d_out;

  // ws layout (bf16 images, all tiles pre-swizzled):
  //   p1img:  8   x 8192 ushorts (128 KB)   preds1 * log2e
  //   p2img:  1152x 8192 ushorts (18.9 MB)  preds2 * log2e
  //   posimg: 1152x 8192 ushorts (18.9 MB)  fmap_tp1 bf16
  ushort* p1img  = (ushort*)d_ws;
  ushort* p2img  = p1img + 8 * 8192;
  ushort* posimg = p2img + 1152 * 8192;

  hipMemsetAsync(d_out, 0, out_size * sizeof(float), stream);
  prep_kernel<<<2320, 256, 0, stream>>>(f_t, fmap_t, fmap_tp1, W1, b1, W2, b2,
                                        p1img, p2img, posimg);
  stdim_main<<<1152, 512, 0, stream>>>(p1img, p2img, posimg, out);
}

// Round 8
// 153.703 us; speedup vs baseline: 4.2758x; 1.0658x over previous
//
#include <hip/hip_runtime.h>
#include <hip/hip_bf16.h>
#include <math.h>

#define LC 18432              // 144*128
#define LOG2E 1.4426950408889634f

typedef short bf16x8 __attribute__((ext_vector_type(8)));
typedef float f32x4 __attribute__((ext_vector_type(4)));

#define MFMA16 __builtin_amdgcn_mfma_f32_16x16x32_bf16

__device__ __forceinline__ float fast_exp2(float x) {
#if __has_builtin(__builtin_amdgcn_exp2f)
  return __builtin_amdgcn_exp2f(x);
#else
  return exp2f(x);
#endif
}
__device__ __forceinline__ float fast_log2(float x) {
#if __has_builtin(__builtin_amdgcn_logf)
  return __builtin_amdgcn_logf(x);
#else
  return log2f(x);
#endif
}

__device__ __forceinline__ ushort f2bf(float x) {
  __hip_bfloat16 h = __float2bfloat16(x);
  return __builtin_bit_cast(ushort, h);
}

// byte offset in a 256-byte-row swizzled tile (128 bf16 cols)
__device__ __forceinline__ int swb(int row, int x) {
  return (row << 8) + (x ^ ((row & 15) << 4));
}
// byte offset in a 512-byte-row swizzled tile (256 bf16 cols)
__device__ __forceinline__ int swb9(int row, int x) {
  return (row << 9) + (x ^ ((row & 15) << 4));
}

// ---------------- preds1 (tiny): p1img[8 tiles][64x128 bf16, swizzled] ----
// grid 32: (rc 0..15) x (dh 0..1); rows rc*32..+32, d dh*64..+64, K=256
__global__ __launch_bounds__(256) void preds1_k(
    const float* __restrict__ f_t, const float* __restrict__ W1,
    const float* __restrict__ b1, ushort* __restrict__ p1img,
    float* __restrict__ out) {
  if (blockIdx.x == 0 && threadIdx.x == 0) *out = 0.f;  // replaces memset
  __shared__ __align__(16) ushort sF[32 * 256];  // 16 KB
  __shared__ __align__(16) ushort sW[64 * 256];  // 32 KB
  const int rc = blockIdx.x >> 1, dh = blockIdx.x & 1;
  const int t = threadIdx.x;
  const int wave = t >> 6, lane = t & 63, lo = lane & 15, hi = lane >> 4;
#pragma unroll
  for (int k = 0; k < 8; ++k) {
    int idx = t + k * 256;
    int row = idx >> 6, c4 = (idx & 63) << 2;
    float4 v = *(const float4*)(f_t + (size_t)(rc * 32 + row) * 256 + c4);
    ushort4 h = {f2bf(v.x), f2bf(v.y), f2bf(v.z), f2bf(v.w)};
    *(ushort4*)((char*)sF + swb9(row, c4 << 1)) = h;
  }
#pragma unroll
  for (int k = 0; k < 16; ++k) {
    int idx = t + k * 256;
    int row = idx >> 6, c4 = (idx & 63) << 2;
    float4 v = *(const float4*)(W1 + (size_t)(dh * 64 + row) * 256 + c4);
    ushort4 h = {f2bf(v.x), f2bf(v.y), f2bf(v.z), f2bf(v.w)};
    *(ushort4*)((char*)sW + swb9(row, c4 << 1)) = h;
  }
  __syncthreads();
  const int rn = (wave & 1) * 16, wd = (wave >> 1) * 32;
  f32x4 acc[2] = {};
#pragma unroll
  for (int s = 0; s < 8; ++s) {
    int x = s * 64 + hi * 16;
    bf16x8 a = *(const bf16x8*)((const char*)sF + swb9(rn + lo, x));
#pragma unroll
    for (int j = 0; j < 2; ++j) {
      bf16x8 b = *(const bf16x8*)((const char*)sW + swb9(wd + j * 16 + lo, x));
      acc[j] = MFMA16(a, b, acc[j], 0, 0, 0);
    }
  }
#pragma unroll
  for (int j = 0; j < 2; ++j) {
    int d = dh * 64 + wd + j * 16 + lo;
    float bb = b1[d];
#pragma unroll
    for (int e = 0; e < 4; ++e) {
      int R = rc * 32 + rn + hi * 4 + e;
      int tile = R >> 6, rin = R & 63;
      *(ushort*)((char*)p1img + (size_t)tile * 16384 + (rin << 8) +
                 ((2 * d) ^ ((rin & 15) << 4))) =
          f2bf((acc[j][e] + bb) * LOG2E);
    }
  }
}

// ---------------- fused main ----------------
// block (l, rb): computes preds2 tile in-block, then logits + online 2^w sum.
__device__ __forceinline__ void load_tile(float4 pv[4], const float* __restrict__ base,
                                          int t) {
#pragma unroll
  for (int k = 0; k < 4; ++k) {
    int idx = t + k * 512;
    int row = idx >> 5, c4 = (idx & 31) << 2;
    pv[k] = *(const float4*)(base + (size_t)row * LC + c4);
  }
}
__device__ __forceinline__ void write_tile(ushort* dstbuf, const float4 pv[4], int t) {
#pragma unroll
  for (int k = 0; k < 4; ++k) {
    int idx = t + k * 512;
    int row = idx >> 5, c4 = (idx & 31) << 2;
    ushort4 h = {f2bf(pv[k].x), f2bf(pv[k].y), f2bf(pv[k].z), f2bf(pv[k].w)};
    *(ushort4*)((char*)dstbuf + swb(row, c4 << 1)) = h;
  }
}

__global__ __launch_bounds__(512) void stdim_fused(
    const ushort* __restrict__ p1img, const float* __restrict__ fmap_t,
    const float* __restrict__ fmap_tp1, const float* __restrict__ W2,
    const float* __restrict__ b2, float* __restrict__ out) {
  __shared__ __align__(16) ushort sP[8192];     // loc -> preds2 tile (16 KB)
  __shared__ __align__(16) ushort sPos[16384];  // phase A: W2 (32 KB); loop: pos dbuf
  __shared__ float s_rows[2][64][2];
  __shared__ float s_diag[2][64];
  __shared__ float s_red[8];

  const int bid = blockIdx.x;
  const int work = (bid & 7) * 144 + (bid >> 3);  // XCD-chunked (1152 % 8 == 0)
  const int l = work >> 3, rb = work & 7;
  const int t = threadIdx.x;
  const int wave = t >> 6, lane = t & 63, lo = lane & 15, hi = lane >> 4;
  const int ty_ = wave >> 2, wr = (wave >> 1) & 1, wc = wave & 1;

  const float* posbase = fmap_tp1 + l * 128;

  // ---- phase A: stage loc -> sP, W2 -> sPos ----
#pragma unroll
  for (int k = 0; k < 4; ++k) {
    int idx = t + k * 512;
    int row = idx >> 5, c4 = (idx & 31) << 2;
    float4 v = *(const float4*)(fmap_t + (size_t)(rb * 64 + row) * LC + l * 128 + c4);
    ushort4 h = {f2bf(v.x), f2bf(v.y), f2bf(v.z), f2bf(v.w)};
    *(ushort4*)((char*)sP + swb(row, c4 << 1)) = h;
  }
#pragma unroll
  for (int k = 0; k < 8; ++k) {
    int idx = t + k * 512;
    int row = idx >> 5, c4 = (idx & 31) << 2;
    float4 v = *(const float4*)(W2 + (size_t)row * 128 + c4);
    ushort4 h = {f2bf(v.x), f2bf(v.y), f2bf(v.z), f2bf(v.w)};
    *(ushort4*)((char*)sPos + swb(row, c4 << 1)) = h;  // rows 0..127, 32 KB
  }
  const int wn = (wave & 1) * 32, wd = (wave >> 1) * 32;  // wave>>1: 0..3
  const float b2a = b2[wd + lo], b2b = b2[wd + 16 + lo];
  // issue pos tiles 0,1 into regs early (written to LDS after W2 is consumed)
  float4 pvA[4], pvB[4];
  load_tile(pvA, posbase, t);
  load_tile(pvB, posbase + (size_t)64 * LC, t);
  __syncthreads();

  // ---- preds2 = loc @ W2^T (MFMA) ----
  f32x4 acc2[2][2] = {};
#pragma unroll
  for (int s = 0; s < 4; ++s) {
    int x = s * 64 + hi * 16;
    bf16x8 a0 = *(const bf16x8*)((const char*)sP + swb(wn + lo, x));
    bf16x8 a1 = *(const bf16x8*)((const char*)sP + swb(wn + 16 + lo, x));
#pragma unroll
    for (int j = 0; j < 2; ++j) {
      bf16x8 b = *(const bf16x8*)((const char*)sPos + swb(wd + j * 16 + lo, x));
      acc2[0][j] = MFMA16(a0, b, acc2[0][j], 0, 0, 0);
      acc2[1][j] = MFMA16(a1, b, acc2[1][j], 0, 0, 0);
    }
  }
  __syncthreads();  // all reads of sP (loc) and sPos (W2) complete

  // write preds2*log2e into sP; write pos tiles 0,1 into sPos dbuf
#pragma unroll
  for (int i2 = 0; i2 < 2; ++i2)
#pragma unroll
    for (int j = 0; j < 2; ++j)
#pragma unroll
      for (int e = 0; e < 4; ++e) {
        int r = wn + i2 * 16 + hi * 4 + e;
        int d = wd + j * 16 + lo;
        *(ushort*)((char*)sP + (r << 8) + ((2 * d) ^ ((r & 15) << 4))) =
            f2bf((acc2[i2][j][e] + (j ? b2b : b2a)) * LOG2E);
      }
  write_tile((ushort*)sPos, pvA, t);
  write_tile((ushort*)((char*)sPos + 16384), pvB, t);
  __syncthreads();  // preds2 + pos tiles 0,1 visible

  // ---- A fragments to regs (loss1 from global p1img; loss2 from sP) ----
  bf16x8 af[2][4];
  if (ty_ == 0) {
    const char* aimg = (const char*)(p1img + (size_t)rb * 8192);
#pragma unroll
    for (int rt = 0; rt < 2; ++rt)
#pragma unroll
      for (int s = 0; s < 4; ++s)
        af[rt][s] = *(const bf16x8*)(aimg + swb(wr * 32 + rt * 16 + lo, s * 64 + hi * 16));
  } else {
#pragma unroll
    for (int rt = 0; rt < 2; ++rt)
#pragma unroll
      for (int s = 0; s < 4; ++s)
        af[rt][s] = *(const bf16x8*)((const char*)sP +
                                     swb(wr * 32 + rt * 16 + lo, s * 64 + hi * 16));
  }

  float sm0[4] = {0.f, 0.f, 0.f, 0.f}, sm1[4] = {0.f, 0.f, 0.f, 0.f};

  // ---- main loop: tile mt in buf[mt&1]; stage tile mt+2 (1 barrier/iter) ----
#pragma unroll
  for (int mt = 0; mt < 8; ++mt) {
    float4 nv[4];
    if (mt < 6) load_tile(nv, posbase + (size_t)((mt + 2) * 64) * LC, t);

    const char* cur = (const char*)sPos + (mt & 1) * 16384;
    f32x4 a00 = {}, a01 = {}, a10 = {}, a11 = {};
#pragma unroll
    for (int s = 0; s < 4; ++s) {
      int x = s * 64 + hi * 16;
      bf16x8 b0 = *(const bf16x8*)(cur + swb(wc * 32 + lo, x));
      bf16x8 b1 = *(const bf16x8*)(cur + swb(wc * 32 + 16 + lo, x));
      a00 = MFMA16(af[0][s], b0, a00, 0, 0, 0);
      a01 = MFMA16(af[0][s], b1, a01, 0, 0, 0);
      a10 = MFMA16(af[1][s], b0, a10, 0, 0, 0);
      a11 = MFMA16(af[1][s], b1, a11, 0, 0, 0);
    }
#pragma unroll
    for (int i = 0; i < 4; ++i) {
      sm0[i] += fast_exp2(a00[i]) + fast_exp2(a01[i]);
      sm1[i] += fast_exp2(a10[i]) + fast_exp2(a11[i]);
    }
    if (mt == rb && wc == wr) {
#pragma unroll
      for (int i = 0; i < 4; ++i) {
        if (lo == hi * 4 + i) {
          s_diag[ty_][wr * 32 + hi * 4 + i] = a00[i];
          s_diag[ty_][wr * 32 + 16 + hi * 4 + i] = a11[i];
        }
      }
    }
    __syncthreads();  // reads of buf[mt&1] complete (all waves)
    if (mt < 6)       // write tile mt+2 into the just-freed buffer;
      write_tile((ushort*)((char*)sPos + (mt & 1) * 16384), nv, t);
    // RAW safety: tile mt+2's reads happen in iter mt+2, after iter mt+1's barrier.
  }

  // ---- reduce the 16 lo-lanes of each row-group ----
#pragma unroll
  for (int i = 0; i < 4; ++i) {
    float v0 = sm0[i], v1 = sm1[i];
#pragma unroll
    for (int st = 1; st <= 8; st <<= 1) {
      v0 += __shfl_xor(v0, st);
      v1 += __shfl_xor(v1, st);
    }
    sm0[i] = v0;
    sm1[i] = v1;
  }
  if (lo == 0) {
#pragma unroll
    for (int i = 0; i < 4; ++i) {
      s_rows[ty_][wr * 32 + hi * 4 + i][wc] = sm0[i];
      s_rows[ty_][wr * 32 + 16 + hi * 4 + i][wc] = sm1[i];
    }
  }
  __syncthreads();

  float part = 0.f;
  if (t < 128) {
    int ty = t >> 6, r = t & 63;
    float tot = s_rows[ty][r][0] + s_rows[ty][r][1];
    part = fast_log2(tot) - s_diag[ty][r];
  }
#pragma unroll
  for (int st = 1; st <= 32; st <<= 1) part += __shfl_xor(part, st);
  if (lane == 0) s_red[wave] = part;
  __syncthreads();
  if (t == 0) {
    float s = 0.f;
#pragma unroll
    for (int w = 0; w < 8; ++w) s += s_red[w];
    atomicAdd(out, s * (0.6931471805599453f / 73728.0f));
  }
}

extern "C" void kernel_launch(void* const* d_in, const int* in_sizes, int n_in,
                              void* d_out, int out_size, void* d_ws, size_t ws_size,
                              hipStream_t stream) {
  const float* f_t      = (const float*)d_in[0];
  const float* fmap_t   = (const float*)d_in[1];
  const float* fmap_tp1 = (const float*)d_in[2];
  const float* W1       = (const float*)d_in[3];
  const float* b1       = (const float*)d_in[4];
  const float* W2       = (const float*)d_in[5];
  const float* b2       = (const float*)d_in[6];
  float* out = (float*)d_out;
  ushort* p1img = (ushort*)d_ws;  // 8 x 8192 ushorts = 128 KB (swizzled bf16)

  preds1_k<<<32, 256, 0, stream>>>(f_t, W1, b1, p1img, out);
  stdim_fused<<<1152, 512, 0, stream>>>(p1img, fmap_t, fmap_tp1, W2, b2, out);
}